// Round 8
// baseline (101.579 us; speedup 1.0000x reference)
//
#include <hip/hip_runtime.h>
#include <stdint.h>

#define N_ROWS 65536
#define K_CODES 1024
#define DIM 256

typedef unsigned int uint;
typedef unsigned short ushort;

// d_ws layout:
//   [0, 4K)       loss accumulator (first 4B)
//   [4K, 8K)      enorm[1024] fp32 (exact, from fp32 E)
//   [8K, +256K)   E8: fp8(e4m3) codebook scaled x256, 256B per code
#define WS_LOSS_OFF  0
#define WS_ENORM_OFF 4096
#define WS_E8_OFF    8192

typedef __attribute__((ext_vector_type(4))) float f32x4;

#define XSCALE 16.0f
#define ESCALE 256.0f
#define SCORE_C 4.8828125e-4f    // 2/(16*256)

__device__ __forceinline__ uint pack4_fp8(float a, float b, float c, float d) {
    uint r = 0;
    r = __builtin_amdgcn_cvt_pk_fp8_f32(a, b, r, false);   // bytes 0-1
    r = __builtin_amdgcn_cvt_pk_fp8_f32(c, d, r, true);    // bytes 2-3
    return r;
}
__device__ __forceinline__ void gload_lds16(const void* g, void* l) {
    __builtin_amdgcn_global_load_lds(
        (const __attribute__((address_space(1))) void*)g,
        (__attribute__((address_space(3))) void*)l, 16, 0, 0);
}

// ---- prep: E -> fp8 codebook (x256) + exact fp32 squared norms -------------
__global__ __launch_bounds__(256) void vq_prep(const float* __restrict__ E,
                                               unsigned char* __restrict__ E8,
                                               float* __restrict__ enorm) {
    int id = blockIdx.x * 256 + threadIdx.x;      // 65536 = 1024 codes * 64 f4
    int code = id >> 6, c4 = id & 63;
    float4 v = *reinterpret_cast<const float4*>(E + (size_t)code * DIM + c4 * 4);
    uint p = pack4_fp8(v.x * ESCALE, v.y * ESCALE, v.z * ESCALE, v.w * ESCALE);
    *reinterpret_cast<uint*>(E8 + (size_t)code * 256 + c4 * 4) = p;

    float s = v.x * v.x + v.y * v.y + v.z * v.z + v.w * v.w;
    #pragma unroll
    for (int m = 32; m >= 1; m >>= 1) s += __shfl_down(s, m, 64);
    if (c4 == 0) enorm[code] = s;
}

// ---- fused main: barrier-free single-wave blocks ---------------------------
// Block = 1 wave = 64 threads, owns 32 rows (m=2). A-frags fp8 in regs
// (aF[2][8] longs = 32 VGPR). B: 64 tiles of 16 codes x 256 k fp8 (4KB),
// wave-private 3-deep rotation staged via global_load_lds; counted
// vmcnt(8) per tile (T4), stage issued 2 tiles ahead. ZERO barriers:
// all sync is wave-local waitcnt -> no convoy, phases self-stagger
// across ~9 resident blocks/CU.
__global__ __launch_bounds__(64, 3) void vq_main(const float* __restrict__ X,
                                                 const unsigned char* __restrict__ E8,
                                                 const float* __restrict__ enorm,
                                                 const float* __restrict__ E,
                                                 float* __restrict__ out,
                                                 float* __restrict__ lossAcc) {
    __shared__ __align__(16) unsigned char bsm[3 * 4096];   // 3 B-tile slots
    __shared__ __align__(16) float enormLds[1024];
    __shared__ float xnormLds[32];
    __shared__ int   bcLds[32];

    const int lane = threadIdx.x;    // 0..63
    const int cl = lane & 15;
    const int kq = lane >> 4;
    const int row0 = blockIdx.x * 32;

    auto stageB = [&](int tile, int slot) {
        unsigned char* dst = bsm + slot * 4096;
        const unsigned char* src = E8 + (size_t)(tile * 16) * 256;
        #pragma unroll
        for (int j = 0; j < 4; ++j) {
            int o = j * 1024 + lane * 16;
            int rr = o >> 8;                         // code row in tile (0..15)
            int cb = (o & 255) ^ ((rr & 7) << 4);    // pre-swizzled source (rule 21)
            gload_lds16(src + rr * 256 + cb, dst + o);
        }
    };

    // issue all LDS staging first (oldest in vmcnt stream):
    // enorm (4 KB = 4 ops) + stage(0) + stage(1) = 12 outstanding
    #pragma unroll
    for (int j = 0; j < 4; ++j) {
        int o = j * 1024 + lane * 16;
        gload_lds16((const unsigned char*)enorm + o,
                    (unsigned char*)enormLds + o);
    }
    stageB(0, 0);
    stageB(1, 1);

    // ---- A phase: global -> fp8 regs (m=2) + exact fp32 row norms ----------
    // (A loads are newer than the staging ops; their data-deps drain them
    //  before the loop, so loop-entry vmcnt counts only enorm+stages.)
    long aF[2][8];
    #pragma unroll
    for (int m = 0; m < 2; ++m) {
        const float* rp = X + (size_t)(row0 + m * 16 + cl) * DIM;
        float s = 0.f;
        #pragma unroll
        for (int ks = 0; ks < 8; ++ks) {
            float4 v0 = *reinterpret_cast<const float4*>(rp + ks * 32 + kq * 8);
            float4 v1 = *reinterpret_cast<const float4*>(rp + ks * 32 + kq * 8 + 4);
            uint lo = pack4_fp8(v0.x * XSCALE, v0.y * XSCALE,
                                v0.z * XSCALE, v0.w * XSCALE);
            uint hi = pack4_fp8(v1.x * XSCALE, v1.y * XSCALE,
                                v1.z * XSCALE, v1.w * XSCALE);
            aF[m][ks] = (long)(((unsigned long long)hi << 32) | lo);
            s = fmaf(v0.x, v0.x, s); s = fmaf(v0.y, v0.y, s);
            s = fmaf(v0.z, v0.z, s); s = fmaf(v0.w, v0.w, s);
            s = fmaf(v1.x, v1.x, s); s = fmaf(v1.y, v1.y, s);
            s = fmaf(v1.z, v1.z, s); s = fmaf(v1.w, v1.w, s);
        }
        s += __shfl_xor(s, 16, 64);
        s += __shfl_xor(s, 32, 64);
        if (kq == 0) xnormLds[m * 16 + cl] = s;
    }

    float best[2][4];
    int bcode[2][4];
    #pragma unroll
    for (int m = 0; m < 2; ++m)
        #pragma unroll
        for (int rr = 0; rr < 4; ++rr) { best[m][rr] = 3.4e38f; bcode[m][rr] = 0; }

    for (int t = 0; t < 64; ++t) {
        if (t <= 61) stageB(t + 2, (t + 2) % 3);   // writes slot (t-1)%3: its
                                                   // reads finished last iter
        // counted wave-local wait: stage(t) landed; t+1,t+2 in flight (T4)
        if (t <= 61)      { asm volatile("s_waitcnt vmcnt(8)" ::: "memory"); }
        else if (t == 62) { asm volatile("s_waitcnt vmcnt(4)" ::: "memory"); }
        else              { asm volatile("s_waitcnt vmcnt(0)" ::: "memory"); }

        const unsigned char* bb = bsm + (t % 3) * 4096;
        float en = enormLds[t * 16 + cl];

        f32x4 acc[2];
        #pragma unroll
        for (int m = 0; m < 2; ++m) {
            f32x4 z = {0.f, 0.f, 0.f, 0.f};
            acc[m] = z;
        }

        __builtin_amdgcn_s_setprio(1);
        #pragma unroll
        for (int ks = 0; ks < 8; ++ks) {
            long bf = *reinterpret_cast<const long*>(
                bb + cl * 256 + ((ks * 32 + kq * 8) ^ ((cl & 7) << 4)));
            #pragma unroll
            for (int m = 0; m < 2; ++m)
                acc[m] = __builtin_amdgcn_mfma_f32_16x16x32_fp8_fp8(
                    aF[m][ks], bf, acc[m], 0, 0, 0);
        }
        __builtin_amdgcn_s_setprio(0);

        // fold (codes ascend across t -> strict < keeps first occurrence)
        int codeN = t * 16 + cl;
        #pragma unroll
        for (int m = 0; m < 2; ++m)
            #pragma unroll
            for (int rr = 0; rr < 4; ++rr) {
                float sc = fmaf(-SCORE_C, acc[m][rr], en);
                if (sc < best[m][rr]) { best[m][rr] = sc; bcode[m][rr] = codeN; }
            }
    }

    // epilogue: cross-cl argmin reduce; C-row = m*16 + kq*4 + rr (m89 layout)
    float lsum = 0.f;
    #pragma unroll
    for (int m = 0; m < 2; ++m)
        #pragma unroll
        for (int rr = 0; rr < 4; ++rr) {
            float b = best[m][rr];
            int cc = bcode[m][rr];
            #pragma unroll
            for (int mask = 1; mask < 16; mask <<= 1) {
                float ob = __shfl_xor(b, mask, 64);
                int oc = __shfl_xor(cc, mask, 64);
                if (ob < b || (ob == b && oc < cc)) { b = ob; cc = oc; }
            }
            if (cl == 0) {
                int row_l = m * 16 + kq * 4 + rr;
                bcLds[row_l] = cc;
                lsum += xnormLds[row_l] + b;   // ||x||^2 + ||e||^2 - 2 x.e
            }
        }
    lsum += __shfl_xor(lsum, 16, 64);
    lsum += __shfl_xor(lsum, 32, 64);
    if (lane == 0) atomicAdd(lossAcc, lsum);

    // out[row] = E[bc[row]] (== x + (q - x) to ~3e-7), fully coalesced
    #pragma unroll 4
    for (int i = 0; i < 32; ++i) {
        int code = bcLds[i];                      // wave-uniform broadcast
        float4 q = *reinterpret_cast<const float4*>(E + (size_t)code * DIM + lane * 4);
        *reinterpret_cast<float4*>(out + (size_t)(row0 + i) * DIM + lane * 4) = q;
    }
}

__global__ void vq_finalize(const float* __restrict__ lossAcc,
                            float* __restrict__ out) {
    out[(size_t)N_ROWS * DIM] = 1.25f * lossAcc[0] / (float)((size_t)N_ROWS * DIM);
}

extern "C" void kernel_launch(void* const* d_in, const int* in_sizes, int n_in,
                              void* d_out, int out_size, void* d_ws, size_t ws_size,
                              hipStream_t stream) {
    const float* X = (const float*)d_in[0];
    const float* E = (const float*)d_in[1];
    float* out = (float*)d_out;

    char* ws = (char*)d_ws;
    float* lossAcc = (float*)(ws + WS_LOSS_OFF);
    float* enorm = (float*)(ws + WS_ENORM_OFF);
    unsigned char* E8 = (unsigned char*)(ws + WS_E8_OFF);

    hipMemsetAsync(lossAcc, 0, 4, stream);
    vq_prep<<<256, 256, 0, stream>>>(E, E8, enorm);
    vq_main<<<N_ROWS / 32, 64, 0, stream>>>(X, E8, enorm, E, out, lossAcc);
    vq_finalize<<<1, 1, 0, stream>>>(lossAcc, out);
}

// Round 9
// 64.402 us; speedup vs baseline: 1.5773x; 1.5773x over previous
//
#include <hip/hip_runtime.h>
#include <stdint.h>

#define N_ROWS 65536
#define K_CODES 1024
#define DIM 256

typedef unsigned int uint;
typedef unsigned short ushort;

// d_ws layout:
//   [0, 4K)       loss accumulator (first 4B)
//   [4K, 8K)      enorm[1024] fp32 (exact, from fp32 E)
//   [8K, +256K)   E8: fp8(e4m3) codebook scaled x256, 256B per code
#define WS_LOSS_OFF  0
#define WS_ENORM_OFF 4096
#define WS_E8_OFF    8192

typedef __attribute__((ext_vector_type(4))) float f32x4;

#define XSCALE 16.0f
#define ESCALE 256.0f
#define SCORE_C 4.8828125e-4f    // 2/(16*256)

__device__ __forceinline__ uint pack4_fp8(float a, float b, float c, float d) {
    uint r = 0;
    r = __builtin_amdgcn_cvt_pk_fp8_f32(a, b, r, false);   // bytes 0-1
    r = __builtin_amdgcn_cvt_pk_fp8_f32(c, d, r, true);    // bytes 2-3
    return r;
}
__device__ __forceinline__ void gload_lds16(const void* g, void* l) {
    __builtin_amdgcn_global_load_lds(
        (const __attribute__((address_space(1))) void*)g,
        (__attribute__((address_space(3))) void*)l, 16, 0, 0);
}

// ---- prep: E -> fp8 codebook (x256) + exact fp32 squared norms -------------
__global__ __launch_bounds__(256) void vq_prep(const float* __restrict__ E,
                                               unsigned char* __restrict__ E8,
                                               float* __restrict__ enorm) {
    int id = blockIdx.x * 256 + threadIdx.x;      // 65536 = 1024 codes * 64 f4
    int code = id >> 6, c4 = id & 63;
    float4 v = *reinterpret_cast<const float4*>(E + (size_t)code * DIM + c4 * 4);
    uint p = pack4_fp8(v.x * ESCALE, v.y * ESCALE, v.z * ESCALE, v.w * ESCALE);
    *reinterpret_cast<uint*>(E8 + (size_t)code * 256 + c4 * 4) = p;

    float s = v.x * v.x + v.y * v.y + v.z * v.z + v.w * v.w;
    #pragma unroll
    for (int m = 32; m >= 1; m >>= 1) s += __shfl_down(s, m, 64);
    if (c4 == 0) enorm[code] = s;
}

// ---- fused main ------------------------------------------------------------
// r3's proven 2-phase block-shared structure + fp8 operands.
// Block: 256 thr = 4 waves, 128 rows (wave w: rows w*32..+31, m=2).
// B: 16 tiles of 64 codes x 256 K fp8 (16KB), double-buffered; per tile:
// __syncthreads -> stage(t+1) into OTHER buffer -> compute(t). The barrier's
// implicit vm-drain covers the 1-ahead stage (a full compute phase to land).
// Grid 512 -> 2 blocks/CU, 8 waves/CU.
__global__ __launch_bounds__(256, 2) void vq_main(const float* __restrict__ X,
                                                  const unsigned char* __restrict__ E8,
                                                  const float* __restrict__ enorm,
                                                  const float* __restrict__ E,
                                                  float* __restrict__ out,
                                                  float* __restrict__ lossAcc) {
    __shared__ __align__(16) unsigned char bsm[2 * 16384];  // 2 x 64-code tiles
    __shared__ float enormLds[1024];
    __shared__ float xnormLds[128];
    __shared__ int   bcLds[128];
    __shared__ float lossSh;

    const int tid = threadIdx.x;
    const int lane = tid & 63;
    const int w = tid >> 6;          // wave 0..3
    const int cl = lane & 15;
    const int kq = lane >> 4;
    const int row0 = blockIdx.x * 128;

    auto stageB = [&](int tile, int buf) {
        unsigned char* dst = bsm + buf * 16384;
        const unsigned char* src = E8 + (size_t)(tile * 64) * 256;
        #pragma unroll
        for (int j = 0; j < 4; ++j) {
            int o = j * 4096 + tid * 16;             // wave-uniform base + lane*16
            int rr = o >> 8;                         // code row in tile (0..63)
            int cb = (o & 255) ^ ((rr & 7) << 4);    // pre-swizzled source (rule 21)
            gload_lds16(src + rr * 256 + cb, dst + o);
        }
    };

    stageB(0, 0);                    // issue first tile ASAP (oldest vmem)

    // enorm -> LDS (1024 f32; one float4 per thread)
    reinterpret_cast<float4*>(enormLds)[tid] =
        reinterpret_cast<const float4*>(enorm)[tid];
    if (tid == 0) lossSh = 0.f;

    // ---- A phase: global -> fp8 regs (m=2) + exact fp32 row norms ----------
    long aF[2][8];
    #pragma unroll
    for (int m = 0; m < 2; ++m) {
        const float* rp = X + (size_t)(row0 + w * 32 + m * 16 + cl) * DIM;
        float s = 0.f;
        #pragma unroll
        for (int ks = 0; ks < 8; ++ks) {
            float4 v0 = *reinterpret_cast<const float4*>(rp + ks * 32 + kq * 8);
            float4 v1 = *reinterpret_cast<const float4*>(rp + ks * 32 + kq * 8 + 4);
            uint lo = pack4_fp8(v0.x * XSCALE, v0.y * XSCALE,
                                v0.z * XSCALE, v0.w * XSCALE);
            uint hi = pack4_fp8(v1.x * XSCALE, v1.y * XSCALE,
                                v1.z * XSCALE, v1.w * XSCALE);
            aF[m][ks] = (long)(((unsigned long long)hi << 32) | lo);
            s = fmaf(v0.x, v0.x, s); s = fmaf(v0.y, v0.y, s);
            s = fmaf(v0.z, v0.z, s); s = fmaf(v0.w, v0.w, s);
            s = fmaf(v1.x, v1.x, s); s = fmaf(v1.y, v1.y, s);
            s = fmaf(v1.z, v1.z, s); s = fmaf(v1.w, v1.w, s);
        }
        s += __shfl_xor(s, 16, 64);
        s += __shfl_xor(s, 32, 64);
        if (kq == 0) xnormLds[w * 32 + m * 16 + cl] = s;
    }

    float best[2][4];
    int bcode[2][4];
    #pragma unroll
    for (int m = 0; m < 2; ++m)
        #pragma unroll
        for (int rr = 0; rr < 4; ++rr) { best[m][rr] = 3.4e38f; bcode[m][rr] = 0; }

    for (int t = 0; t < 16; ++t) {
        __syncthreads();                 // stage(t) + (t==0: A/enorm) visible
        if (t < 15) stageB(t + 1, (t + 1) & 1);   // writer -> other buffer

        const unsigned char* bb = bsm + (t & 1) * 16384;
        float en[4];
        #pragma unroll
        for (int n = 0; n < 4; ++n) en[n] = enormLds[t * 64 + n * 16 + cl];

        f32x4 acc[2][4];
        #pragma unroll
        for (int m = 0; m < 2; ++m)
            #pragma unroll
            for (int n = 0; n < 4; ++n) {
                f32x4 z = {0.f, 0.f, 0.f, 0.f};
                acc[m][n] = z;
            }

        __builtin_amdgcn_s_setprio(1);
        #pragma unroll
        for (int ks = 0; ks < 8; ++ks) {
            #pragma unroll
            for (int n = 0; n < 4; ++n) {
                long bf = *reinterpret_cast<const long*>(
                    bb + (size_t)(n * 16 + cl) * 256
                       + ((ks * 32 + kq * 8) ^ ((cl & 7) << 4)));
                #pragma unroll
                for (int m = 0; m < 2; ++m)
                    acc[m][n] = __builtin_amdgcn_mfma_f32_16x16x32_fp8_fp8(
                        aF[m][ks], bf, acc[m][n], 0, 0, 0);
            }
        }
        __builtin_amdgcn_s_setprio(0);

        // fold (codes ascend -> strict < keeps first occurrence)
        #pragma unroll
        for (int n = 0; n < 4; ++n) {
            int codeN = t * 64 + n * 16 + cl;
            #pragma unroll
            for (int m = 0; m < 2; ++m)
                #pragma unroll
                for (int rr = 0; rr < 4; ++rr) {
                    float sc = fmaf(-SCORE_C, acc[m][n][rr], en[n]);
                    if (sc < best[m][rr]) { best[m][rr] = sc; bcode[m][rr] = codeN; }
                }
        }
    }

    // epilogue: cross-cl argmin reduce; C-row = m*16 + kq*4 + rr (m89 layout)
    float lsum = 0.f;
    #pragma unroll
    for (int m = 0; m < 2; ++m)
        #pragma unroll
        for (int rr = 0; rr < 4; ++rr) {
            float b = best[m][rr];
            int cc = bcode[m][rr];
            #pragma unroll
            for (int mask = 1; mask < 16; mask <<= 1) {
                float ob = __shfl_xor(b, mask, 64);
                int oc = __shfl_xor(cc, mask, 64);
                if (ob < b || (ob == b && oc < cc)) { b = ob; cc = oc; }
            }
            if (cl == 0) {
                int row_l = w * 32 + m * 16 + kq * 4 + rr;
                bcLds[row_l] = cc;
                lsum += xnormLds[row_l] + b;   // ||x||^2 + ||e||^2 - 2 x.e
            }
        }
    lsum += __shfl_xor(lsum, 16, 64);
    lsum += __shfl_xor(lsum, 32, 64);
    if (lane == 0) atomicAdd(&lossSh, lsum);
    __syncthreads();                          // bcLds + lossSh ready

    // out[row] = E[bc[row]]  (== x + (q - x) to ~3e-7)
    #pragma unroll 4
    for (int i = 0; i < 32; ++i) {
        int g = i * 256 + tid;                // 8192 f4 = 128 rows x 64
        int rr = g >> 6, c4 = g & 63;
        int code = bcLds[rr];
        float4 q = *reinterpret_cast<const float4*>(E + (size_t)code * DIM + c4 * 4);
        *reinterpret_cast<float4*>(out + (size_t)(row0 + rr) * DIM + c4 * 4) = q;
    }
    if (tid == 0) atomicAdd(lossAcc, lossSh);
}

__global__ void vq_finalize(const float* __restrict__ lossAcc,
                            float* __restrict__ out) {
    out[(size_t)N_ROWS * DIM] = 1.25f * lossAcc[0] / (float)((size_t)N_ROWS * DIM);
}

extern "C" void kernel_launch(void* const* d_in, const int* in_sizes, int n_in,
                              void* d_out, int out_size, void* d_ws, size_t ws_size,
                              hipStream_t stream) {
    const float* X = (const float*)d_in[0];
    const float* E = (const float*)d_in[1];
    float* out = (float*)d_out;

    char* ws = (char*)d_ws;
    float* lossAcc = (float*)(ws + WS_LOSS_OFF);
    float* enorm = (float*)(ws + WS_ENORM_OFF);
    unsigned char* E8 = (unsigned char*)(ws + WS_E8_OFF);

    hipMemsetAsync(lossAcc, 0, 4, stream);
    vq_prep<<<256, 256, 0, stream>>>(E, E8, enorm);
    vq_main<<<N_ROWS / 128, 256, 0, stream>>>(X, E8, enorm, E, out, lossAcc);
    vq_finalize<<<1, 1, 0, stream>>>(lossAcc, out);
}

// Round 10
// 54.743 us; speedup vs baseline: 1.8556x; 1.1764x over previous
//
#include <hip/hip_runtime.h>
#include <stdint.h>

#define N_ROWS 65536
#define K_CODES 1024
#define DIM 256

typedef unsigned int uint;
typedef unsigned short ushort;

// d_ws layout:
//   [0, 4K)       loss accumulator (first 4B)
//   [4K, 8K)      enorm[1024] fp32 (exact, from fp32 E)
//   [8K, +256K)   E8: fp8(e4m3) codebook scaled x256, 256B per code (k-contig)
#define WS_LOSS_OFF  0
#define WS_ENORM_OFF 4096
#define WS_E8_OFF    8192

typedef __attribute__((ext_vector_type(4))) float f32x4;
typedef __attribute__((ext_vector_type(4))) int   i32x4;
typedef __attribute__((ext_vector_type(8))) int   i32x8;

#define XSCALE 16.0f
#define ESCALE 256.0f
#define SCORE_C 4.8828125e-4f    // 2/(16*256)
#define SCALE1 0x7F7F7F7Fu       // E8M0 identity in every byte (opsel-proof)

__device__ __forceinline__ uint pack4_fp8(float a, float b, float c, float d) {
    uint r = 0;
    r = __builtin_amdgcn_cvt_pk_fp8_f32(a, b, r, false);   // bytes 0-1
    r = __builtin_amdgcn_cvt_pk_fp8_f32(c, d, r, true);    // bytes 2-3
    return r;
}
__device__ __forceinline__ void gload_lds16(const void* g, void* l) {
    __builtin_amdgcn_global_load_lds(
        (const __attribute__((address_space(1))) void*)g,
        (__attribute__((address_space(3))) void*)l, 16, 0, 0);
}

// ---- prep: E -> fp8 codebook (x256) + exact fp32 squared norms -------------
__global__ __launch_bounds__(256) void vq_prep(const float* __restrict__ E,
                                               unsigned char* __restrict__ E8,
                                               float* __restrict__ enorm) {
    int id = blockIdx.x * 256 + threadIdx.x;      // 65536 = 1024 codes * 64 f4
    int code = id >> 6, c4 = id & 63;
    float4 v = *reinterpret_cast<const float4*>(E + (size_t)code * DIM + c4 * 4);
    uint p = pack4_fp8(v.x * ESCALE, v.y * ESCALE, v.z * ESCALE, v.w * ESCALE);
    *reinterpret_cast<uint*>(E8 + (size_t)code * 256 + c4 * 4) = p;

    float s = v.x * v.x + v.y * v.y + v.z * v.z + v.w * v.w;
    #pragma unroll
    for (int m = 32; m >= 1; m >>= 1) s += __shfl_down(s, m, 64);
    if (c4 == 0) enorm[code] = s;
}

// ---- fused main ------------------------------------------------------------
// r9 structure + MX-scaled fp8 K=128 MFMA (2x rate, identity scales).
// Block: 256 thr = 4 waves, 128 rows (wave w: rows w*32..+31, m=2).
// B: 8 tiles of 128 codes x 256 K fp8 (32KB), double-buffered; per tile:
// __syncthreads -> stage(t+1) into other buffer -> compute(t).
// Per wave-tile: 32 MFMA (2ks x 8n x 2m), 32 paired ds_read_b128.
// Grid 512 -> 2 blocks/CU, 8 waves/CU.
__global__ __launch_bounds__(256, 2) void vq_main(const float* __restrict__ X,
                                                  const unsigned char* __restrict__ E8,
                                                  const float* __restrict__ enorm,
                                                  const float* __restrict__ E,
                                                  float* __restrict__ out,
                                                  float* __restrict__ lossAcc) {
    __shared__ __align__(16) unsigned char bsm[2 * 32768];  // 2 x 128-code tiles
    __shared__ float enormLds[1024];
    __shared__ float xnormLds[128];
    __shared__ int   bcLds[128];
    __shared__ float lossSh;

    const int tid = threadIdx.x;
    const int lane = tid & 63;
    const int w = tid >> 6;          // wave 0..3
    const int cl = lane & 15;
    const int kq = lane >> 4;
    const int row0 = blockIdx.x * 128;
    const int key = (cl & 7) << 4;   // read-side XOR swizzle (bits 4-6)

    auto stageB = [&](int tile, int buf) {
        unsigned char* dst = bsm + buf * 32768;
        const unsigned char* src = E8 + (size_t)(tile * 128) * 256;
        #pragma unroll
        for (int j = 0; j < 8; ++j) {
            int o = j * 4096 + tid * 16;             // linear LDS dest
            int rr = o >> 8;                         // code row in tile (0..127)
            int cb = (o & 255) ^ ((rr & 7) << 4);    // pre-swizzled source (rule 21)
            gload_lds16(src + rr * 256 + cb, dst + o);
        }
    };

    stageB(0, 0);                    // issue first tile ASAP (oldest vmem)

    // enorm -> LDS (1024 f32; one float4 per thread)
    reinterpret_cast<float4*>(enormLds)[tid] =
        reinterpret_cast<const float4*>(enorm)[tid];
    if (tid == 0) lossSh = 0.f;

    // ---- A phase: global -> fp8 regs (m=2, K=128 frags) + exact row norms --
    // A-frag for MFMA step ks: row = base+cl, k = ks*128 + kq*32 .. +32.
    i32x8 aF[2][2];
    #pragma unroll
    for (int m = 0; m < 2; ++m) {
        const float* rp = X + (size_t)(row0 + w * 32 + m * 16 + cl) * DIM;
        float s = 0.f;
        #pragma unroll
        for (int ks = 0; ks < 2; ++ks) {
            const float* p = rp + ks * 128 + kq * 32;
            uint u[8];
            #pragma unroll
            for (int q = 0; q < 8; ++q) {
                float4 v = *reinterpret_cast<const float4*>(p + q * 4);
                u[q] = pack4_fp8(v.x * XSCALE, v.y * XSCALE,
                                 v.z * XSCALE, v.w * XSCALE);
                s = fmaf(v.x, v.x, s); s = fmaf(v.y, v.y, s);
                s = fmaf(v.z, v.z, s); s = fmaf(v.w, v.w, s);
            }
            i32x8 f = {(int)u[0], (int)u[1], (int)u[2], (int)u[3],
                       (int)u[4], (int)u[5], (int)u[6], (int)u[7]};
            aF[m][ks] = f;
        }
        s += __shfl_xor(s, 16, 64);
        s += __shfl_xor(s, 32, 64);
        if (kq == 0) xnormLds[w * 32 + m * 16 + cl] = s;
    }

    float best[2][4];
    int bcode[2][4];
    #pragma unroll
    for (int m = 0; m < 2; ++m)
        #pragma unroll
        for (int rr = 0; rr < 4; ++rr) { best[m][rr] = 3.4e38f; bcode[m][rr] = 0; }

    for (int t = 0; t < 8; ++t) {
        __syncthreads();                 // stage(t) + (t==0: A/enorm) visible
        if (t < 7) stageB(t + 1, (t + 1) & 1);   // writer -> other buffer

        const unsigned char* bb = bsm + (t & 1) * 32768;
        float en[8];
        #pragma unroll
        for (int n = 0; n < 8; ++n) en[n] = enormLds[t * 128 + n * 16 + cl];

        f32x4 acc[2][8];
        #pragma unroll
        for (int m = 0; m < 2; ++m)
            #pragma unroll
            for (int n = 0; n < 8; ++n) {
                f32x4 z = {0.f, 0.f, 0.f, 0.f};
                acc[m][n] = z;
            }

        __builtin_amdgcn_s_setprio(1);
        #pragma unroll
        for (int ks = 0; ks < 2; ++ks) {
            #pragma unroll
            for (int n = 0; n < 8; ++n) {
                const unsigned char* rbase = bb + (size_t)(n * 16 + cl) * 256;
                int l0 = ks * 128 + kq * 32;
                i32x4 lo = *reinterpret_cast<const i32x4*>(rbase + (l0 ^ key));
                i32x4 hi = *reinterpret_cast<const i32x4*>(rbase + ((l0 + 16) ^ key));
                i32x8 bf = __builtin_shufflevector(lo, hi, 0, 1, 2, 3, 4, 5, 6, 7);
                #pragma unroll
                for (int m = 0; m < 2; ++m)
                    acc[m][n] = __builtin_amdgcn_mfma_scale_f32_16x16x128_f8f6f4(
                        aF[m][ks], bf, acc[m][n],
                        0, 0,                 // cbsz=fp8(A), blgp=fp8(B)
                        0, SCALE1,            // opselA, scaleA (identity)
                        0, SCALE1);           // opselB, scaleB (identity)
            }
        }
        __builtin_amdgcn_s_setprio(0);

        // fold (codes ascend -> strict < keeps first occurrence)
        #pragma unroll
        for (int n = 0; n < 8; ++n) {
            int codeN = t * 128 + n * 16 + cl;
            #pragma unroll
            for (int m = 0; m < 2; ++m)
                #pragma unroll
                for (int rr = 0; rr < 4; ++rr) {
                    float sc = fmaf(-SCORE_C, acc[m][n][rr], en[n]);
                    if (sc < best[m][rr]) { best[m][rr] = sc; bcode[m][rr] = codeN; }
                }
        }
    }

    // epilogue: cross-cl argmin reduce; C-row = m*16 + kq*4 + rr (m89 layout)
    float lsum = 0.f;
    #pragma unroll
    for (int m = 0; m < 2; ++m)
        #pragma unroll
        for (int rr = 0; rr < 4; ++rr) {
            float b = best[m][rr];
            int cc = bcode[m][rr];
            #pragma unroll
            for (int mask = 1; mask < 16; mask <<= 1) {
                float ob = __shfl_xor(b, mask, 64);
                int oc = __shfl_xor(cc, mask, 64);
                if (ob < b || (ob == b && oc < cc)) { b = ob; cc = oc; }
            }
            if (cl == 0) {
                int row_l = w * 32 + m * 16 + kq * 4 + rr;
                bcLds[row_l] = cc;
                lsum += xnormLds[row_l] + b;   // ||x||^2 + ||e||^2 - 2 x.e
            }
        }
    lsum += __shfl_xor(lsum, 16, 64);
    lsum += __shfl_xor(lsum, 32, 64);
    if (lane == 0) atomicAdd(&lossSh, lsum);
    __syncthreads();                          // bcLds + lossSh ready

    // out[row] = E[bc[row]] (== x + (q - x) to ~3e-7); nontemporal streaming
    #pragma unroll 4
    for (int i = 0; i < 32; ++i) {
        int g = i * 256 + tid;                // 8192 f4 = 128 rows x 64
        int rr = g >> 6, c4 = g & 63;
        int code = bcLds[rr];
        f32x4 q = *reinterpret_cast<const f32x4*>(E + (size_t)code * DIM + c4 * 4);
        __builtin_nontemporal_store(q,
            reinterpret_cast<f32x4*>(out + (size_t)(row0 + rr) * DIM + c4 * 4));
    }
    if (tid == 0) atomicAdd(lossAcc, lossSh);
}

__global__ void vq_finalize(const float* __restrict__ lossAcc,
                            float* __restrict__ out) {
    out[(size_t)N_ROWS * DIM] = 1.25f * lossAcc[0] / (float)((size_t)N_ROWS * DIM);
}

extern "C" void kernel_launch(void* const* d_in, const int* in_sizes, int n_in,
                              void* d_out, int out_size, void* d_ws, size_t ws_size,
                              hipStream_t stream) {
    const float* X = (const float*)d_in[0];
    const float* E = (const float*)d_in[1];
    float* out = (float*)d_out;

    char* ws = (char*)d_ws;
    float* lossAcc = (float*)(ws + WS_LOSS_OFF);
    float* enorm = (float*)(ws + WS_ENORM_OFF);
    unsigned char* E8 = (unsigned char*)(ws + WS_E8_OFF);

    hipMemsetAsync(lossAcc, 0, 4, stream);
    vq_prep<<<256, 256, 0, stream>>>(E, E8, enorm);
    vq_main<<<N_ROWS / 128, 256, 0, stream>>>(X, E8, enorm, E, out, lossAcc);
    vq_finalize<<<1, 1, 0, stream>>>(lossAcc, out);
}